// Round 3
// baseline (110.113 us; speedup 1.0000x reference)
//
#include <hip/hip_runtime.h>

#define HGT 128
#define WID 128
#define HW  (HGT*WID)        // 16384
#define CIN 64
#define NPIX (4*HW)          // 65536 pixels total
#define TS 16                // pass2 tile side
#define HS 24                // halo side (TS + 2*4)
#define HPX (HS*HS)          // 576

// ---------------------------------------------------------------------------
// Pass 1: per-pixel 1x1 convs f1/f2 (16 ch each), |f2|^2, bilinear upsample.
// Weights staged in LDS transposed [c][32], wave-uniform reads -> broadcast.
// unroll 16: 16 independent global loads in flight per wait (MLP: 4 waves/CU
// x 16 x 256B = 16 KB/CU in flight > 9.2 KB BW-latency product).
// ---------------------------------------------------------------------------
__global__ __launch_bounds__(256) void pass1_kernel(
    const float* __restrict__ delta, const float* __restrict__ outlo,
    const float* __restrict__ w1, const float* __restrict__ b1,
    const float* __restrict__ w2, const float* __restrict__ b2,
    float4* __restrict__ f1p, float4* __restrict__ f2p, float4* __restrict__ rec)
{
    __shared__ float wlds[64][32];   // [c][o]; o<16 -> w1[o], o>=16 -> w2[o-16]
    {
        const int t = threadIdx.x;
#pragma unroll
        for (int s = 0; s < 8; ++s) {
            const int idx = t + s * 256;          // 0..2047
            const int c = idx >> 5, o = idx & 31;
            wlds[c][o] = (o < 16) ? w1[o * 64 + c] : w2[(o - 16) * 64 + c];
        }
    }
    __syncthreads();

    const int g = blockIdx.x * 256 + threadIdx.x;   // 0..65535
    const int n = g >> 14;
    const int p = g & (HW - 1);

    float f1a[16], f2a[16];
#pragma unroll
    for (int o = 0; o < 16; ++o) { f1a[o] = b1[o]; f2a[o] = b2[o]; }

    const float* dbase = delta + n * CIN * HW + p;
#pragma unroll 16
    for (int c = 0; c < CIN; ++c) {
        const float d = dbase[c * HW];
        const float4* wr = (const float4*)(&wlds[c][0]);  // uniform -> broadcast
#pragma unroll
        for (int k = 0; k < 4; ++k) {
            const float4 wv = wr[k];
            f1a[4*k+0] = fmaf(wv.x, d, f1a[4*k+0]);
            f1a[4*k+1] = fmaf(wv.y, d, f1a[4*k+1]);
            f1a[4*k+2] = fmaf(wv.z, d, f1a[4*k+2]);
            f1a[4*k+3] = fmaf(wv.w, d, f1a[4*k+3]);
        }
#pragma unroll
        for (int k = 0; k < 4; ++k) {
            const float4 wv = wr[4 + k];
            f2a[4*k+0] = fmaf(wv.x, d, f2a[4*k+0]);
            f2a[4*k+1] = fmaf(wv.y, d, f2a[4*k+1]);
            f2a[4*k+2] = fmaf(wv.z, d, f2a[4*k+2]);
            f2a[4*k+3] = fmaf(wv.w, d, f2a[4*k+3]);
        }
    }

    float f2sq = 0.f;
#pragma unroll
    for (int o = 0; o < 16; ++o) f2sq = fmaf(f2a[o], f2a[o], f2sq);

#pragma unroll
    for (int k = 0; k < 4; ++k) {
        f1p[k * NPIX + g] = make_float4(f1a[4*k], f1a[4*k+1], f1a[4*k+2], f1a[4*k+3]);
        f2p[k * NPIX + g] = make_float4(f2a[4*k], f2a[4*k+1], f2a[4*k+2], f2a[4*k+3]);
    }

    // bilinear align_corners upsample of out [N,2,64,64] at (y,x)
    const int y = p >> 7, x = p & 127;
    const float ys = (float)(y * 63) / 127.0f;
    const float xs = (float)(x * 63) / 127.0f;
    const int iy0 = (int)ys, ix0 = (int)xs;
    const float fy = ys - (float)iy0, fx = xs - (float)ix0;
    const int iy1 = min(iy0 + 1, 63), ix1 = min(ix0 + 1, 63);
    const float* ob = outlo + n * 2 * 4096;
    float o01[2];
#pragma unroll
    for (int cc = 0; cc < 2; ++cc) {
        const float* oc = ob + cc * 4096;
        const float v00 = oc[iy0*64+ix0], v01 = oc[iy0*64+ix1];
        const float v10 = oc[iy1*64+ix0], v11 = oc[iy1*64+ix1];
        const float top = v00 + fx * (v01 - v00);
        const float bot = v10 + fx * (v11 - v10);
        o01[cc] = top + fy * (bot - top);
    }
    rec[g] = make_float4(o01[0], o01[1], f2sq, 0.f);
}

// 16-FMA dot of the register f1 fragment against one halo pixel's 4 f2 planes.
#define DOT16(fr, A, B, C, D, out)                                             \
    {                                                                          \
        float d0 = fr[0]*A.x, d1 = fr[1]*A.y, d2 = fr[2]*A.z, d3 = fr[3]*A.w;  \
        d0 = fmaf(fr[ 4], B.x, d0); d1 = fmaf(fr[ 5], B.y, d1);                \
        d2 = fmaf(fr[ 6], B.z, d2); d3 = fmaf(fr[ 7], B.w, d3);                \
        d0 = fmaf(fr[ 8], C.x, d0); d1 = fmaf(fr[ 9], C.y, d1);                \
        d2 = fmaf(fr[10], C.z, d2); d3 = fmaf(fr[11], C.w, d3);                \
        d0 = fmaf(fr[12], D.x, d0); d1 = fmaf(fr[13], D.y, d1);                \
        d2 = fmaf(fr[14], D.z, d2); d3 = fmaf(fr[15], D.w, d3);                \
        out = (d0 + d1) + (d2 + d3);                                           \
    }

// One tap: halo index h, ab value av (already in a register) -> accumulate.
#define TAP(h, av)                                                             \
    {                                                                          \
        const float4 A = sf[0][h], B = sf[1][h];                               \
        const float4 C = sf[2][h], D = sf[3][h];                               \
        float dot;                                                             \
        DOT16(f1r, A, B, C, D, dot);                                           \
        const float4 R = sf[4][h];                                             \
        float e = fmaf(-gd, R.z, fmaf(gd2, dot, c0));                          \
        e = fmaf(gs, (av), e);                                                 \
        const float w = __expf(e);                                             \
        s_ += w;                                                               \
        a0 = fmaf(w, R.x, a0);                                                 \
        a1 = fmaf(w, R.y, a1);                                                 \
    }

// ---------------------------------------------------------------------------
// Pass 2, v4: MLP-first. Round-2 inference: pass2 ~26 us, still ~6x over its
// 4.4 us BW floor. Mechanism: the tap loop kept <=2 ab loads in flight per
// wave (8 KB/CU < the 9.2 KB BW*latency product) and re-paid ~700 cy HBM
// latency serially every 2 taps. Fix: prefetch ALL 20(+1) ab taps per thread
// into statically-indexed registers up front, f1 fragment too, halo-fill
// loads issued first -> ~80 KB/CU in flight, ONE vmcnt drain at the barrier.
// After the barrier the tap loop is pure LDS+VALU (zero global ops).
// Thread map unchanged from round 2 (verified): px = t&255, quarter q = t>>8,
// taps tau = q, q+4, ..., plus tau=80 on q3; linear partial-sum merge via LDS.
// Occupancy: 16 waves/CU, VGPR ~80 (f1r 16 + abv 20 + halo 20 + acc/temps).
// ---------------------------------------------------------------------------
__global__ __launch_bounds__(1024, 4) void pass2_kernel(
    const float4* __restrict__ f1p, const float4* __restrict__ f2p,
    const float4* __restrict__ rec, const float* __restrict__ ab,
    const float* __restrict__ gdp, const float* __restrict__ gsp,
    float* __restrict__ outp)
{
    __shared__ float4 sf[5][HPX];      // 46080 B: 4 f2 planes + (r0,r1,f2sq)
    __shared__ float part[3][3][256];  // 9216 B: quarters 1..3 partials

    const int t = threadIdx.x;         // 0..1023
    const int n = blockIdx.z;
    const int bx = blockIdx.x * TS, by = blockIdx.y * TS;

    const float gd = gdp[0], gs = gsp[0];

    // ---- halo fill: issue the 5 plane loads first (threads 0..575) ----
    float4 h0, h1, h2, h3, h4;
    if (t < HPX) {
        const int hy = t / 24, hx = t - hy * 24;
        int gy = by - 4 + hy; gy = gy < 0 ? -gy : (gy > 127 ? 254 - gy : gy);
        int gx = bx - 4 + hx; gx = gx < 0 ? -gx : (gx > 127 ? 254 - gx : gx);
        const int gp = n * HW + gy * 128 + gx;
        h0 = f2p[0 * NPIX + gp];
        h1 = f2p[1 * NPIX + gp];
        h2 = f2p[2 * NPIX + gp];
        h3 = f2p[3 * NPIX + gp];
        h4 = rec[gp];
    }

    const int px = t & 255;            // pixel within tile
    const int q  = t >> 8;             // tap quarter 0..3 (wave-uniform)
    const int tx = px & 15, ty = px >> 4;
    const int p = (by + ty) * 128 + (bx + tx);
    const int g = n * HW + p;

    // ---- prefetch f1 fragment + ALL owned ab taps into registers ----
    float f1r[16];
#pragma unroll
    for (int k = 0; k < 4; ++k) {
        const float4 v = f1p[k * NPIX + g];
        f1r[4*k] = v.x; f1r[4*k+1] = v.y; f1r[4*k+2] = v.z; f1r[4*k+3] = v.w;
    }
    const float* abq = ab + (size_t)n * 81 * HW + p + (size_t)q * HW;
    float abv[20];
#pragma unroll
    for (int it = 0; it < 20; ++it) abv[it] = abq[(size_t)it * 4 * HW];
    float ab80 = 0.f;
    if (q == 3) ab80 = abq[(size_t)77 * HW];   // tau = 3 + 77 = 80

    // ---- LDS writes for the halo, then one drain at the barrier ----
    if (t < HPX) {
        sf[0][t] = h0; sf[1][t] = h1; sf[2][t] = h2; sf[3][t] = h3; sf[4][t] = h4;
    }

    float f1sq = 0.f;
#pragma unroll
    for (int o = 0; o < 16; ++o) f1sq = fmaf(f1r[o], f1r[o], f1sq);
    const float c0 = -gd * f1sq;
    const float gd2 = 2.0f * gd;

    __syncthreads();

    // ---- pure LDS+VALU tap loop (all operands already resident) ----
    float s_ = 0.f, a0 = 0.f, a1 = 0.f;
    int jj = q;                                   // tap col j (wave-uniform)
    int h  = ty * HS + tx + q;                    // halo idx for (i=0, j=q)
#pragma unroll
    for (int it = 0; it < 20; ++it) {
        TAP(h, abv[it]);
        jj += 4;
        const bool carry = (jj >= 9);
        jj -= carry ? 9 : 0;
        h  += carry ? 19 : 4;                     // +4, or +HS-5 on row carry
    }
    if (q == 3) {                                 // extra tap tau=80 (i=8,j=8)
        const int h80 = (ty + 8) * HS + tx + 8;
        TAP(h80, ab80);
    }

    // ---- merge quarters (linear sums; verified rounds 1-2) ----
    if (q > 0) {
        part[q - 1][0][px] = s_;
        part[q - 1][1][px] = a0;
        part[q - 1][2][px] = a1;
    }
    __syncthreads();
    if (q == 0) {
#pragma unroll
        for (int k = 0; k < 3; ++k) {
            s_ += part[k][0][px];
            a0 += part[k][1][px];
            a1 += part[k][2][px];
        }
        const float inv = 1.0f / s_;
        outp[(n * 2 + 0) * HW + p] = a0 * inv;
        outp[(n * 2 + 1) * HW + p] = a1 * inv;
    }
}

extern "C" void kernel_launch(void* const* d_in, const int* in_sizes, int n_in,
                              void* d_out, int out_size, void* d_ws, size_t ws_size,
                              hipStream_t stream) {
    const float* delta = (const float*)d_in[0];   // [4,64,128,128]
    const float* outlo = (const float*)d_in[1];   // [4,2,64,64]
    const float* ab    = (const float*)d_in[2];   // [4,81,16384]
    const float* w1    = (const float*)d_in[3];   // [16,64]
    const float* b1    = (const float*)d_in[4];   // [16]
    const float* w2    = (const float*)d_in[5];   // [16,64]
    const float* b2    = (const float*)d_in[6];   // [16]
    const float* gd    = (const float*)d_in[7];   // scalar
    const float* gs    = (const float*)d_in[8];   // scalar
    float* outp = (float*)d_out;                  // [4,2,128,128]

    float4* f1p = (float4*)d_ws;                  // 4 MiB (4 planes x NPIX)
    float4* f2p = f1p + (size_t)4 * NPIX;         // 4 MiB
    float4* rec = f2p + (size_t)4 * NPIX;         // 1 MiB

    pass1_kernel<<<dim3(256), dim3(256), 0, stream>>>(delta, outlo, w1, b1, w2, b2,
                                                      f1p, f2p, rec);
    pass2_kernel<<<dim3(8, 8, 4), dim3(1024), 0, stream>>>(f1p, f2p, rec, ab,
                                                           gd, gs, outp);
}

// Round 4
// 108.313 us; speedup vs baseline: 1.0166x; 1.0166x over previous
//
#include <hip/hip_runtime.h>

#define HGT 128
#define WID 128
#define HW  (HGT*WID)        // 16384
#define CIN 64
#define NPIX (4*HW)          // 65536 pixels total
#define TS 16                // pass2 tile side
#define HS 24                // halo side (TS + 2*4)
#define HPX (HS*HS)          // 576

// ---------------------------------------------------------------------------
// Pass 1: per-pixel 1x1 convs f1/f2 (16 ch each), |f2|^2, bilinear upsample.
// Weights staged in LDS transposed [c][32], wave-uniform reads -> broadcast.
// unroll 8 (round-2 proven config; unroll 16 in round 3 bought nothing).
// ---------------------------------------------------------------------------
__global__ __launch_bounds__(256) void pass1_kernel(
    const float* __restrict__ delta, const float* __restrict__ outlo,
    const float* __restrict__ w1, const float* __restrict__ b1,
    const float* __restrict__ w2, const float* __restrict__ b2,
    float4* __restrict__ f1p, float4* __restrict__ f2p, float4* __restrict__ rec)
{
    __shared__ float wlds[64][32];   // [c][o]; o<16 -> w1[o], o>=16 -> w2[o-16]
    {
        const int t = threadIdx.x;
#pragma unroll
        for (int s = 0; s < 8; ++s) {
            const int idx = t + s * 256;          // 0..2047
            const int c = idx >> 5, o = idx & 31;
            wlds[c][o] = (o < 16) ? w1[o * 64 + c] : w2[(o - 16) * 64 + c];
        }
    }
    __syncthreads();

    const int g = blockIdx.x * 256 + threadIdx.x;   // 0..65535
    const int n = g >> 14;
    const int p = g & (HW - 1);

    float f1a[16], f2a[16];
#pragma unroll
    for (int o = 0; o < 16; ++o) { f1a[o] = b1[o]; f2a[o] = b2[o]; }

    const float* dbase = delta + n * CIN * HW + p;
#pragma unroll 8
    for (int c = 0; c < CIN; ++c) {
        const float d = dbase[c * HW];
        const float4* wr = (const float4*)(&wlds[c][0]);  // uniform -> broadcast
#pragma unroll
        for (int k = 0; k < 4; ++k) {
            const float4 wv = wr[k];
            f1a[4*k+0] = fmaf(wv.x, d, f1a[4*k+0]);
            f1a[4*k+1] = fmaf(wv.y, d, f1a[4*k+1]);
            f1a[4*k+2] = fmaf(wv.z, d, f1a[4*k+2]);
            f1a[4*k+3] = fmaf(wv.w, d, f1a[4*k+3]);
        }
#pragma unroll
        for (int k = 0; k < 4; ++k) {
            const float4 wv = wr[4 + k];
            f2a[4*k+0] = fmaf(wv.x, d, f2a[4*k+0]);
            f2a[4*k+1] = fmaf(wv.y, d, f2a[4*k+1]);
            f2a[4*k+2] = fmaf(wv.z, d, f2a[4*k+2]);
            f2a[4*k+3] = fmaf(wv.w, d, f2a[4*k+3]);
        }
    }

    float f2sq = 0.f;
#pragma unroll
    for (int o = 0; o < 16; ++o) f2sq = fmaf(f2a[o], f2a[o], f2sq);

#pragma unroll
    for (int k = 0; k < 4; ++k) {
        f1p[k * NPIX + g] = make_float4(f1a[4*k], f1a[4*k+1], f1a[4*k+2], f1a[4*k+3]);
        f2p[k * NPIX + g] = make_float4(f2a[4*k], f2a[4*k+1], f2a[4*k+2], f2a[4*k+3]);
    }

    // bilinear align_corners upsample of out [N,2,64,64] at (y,x)
    const int y = p >> 7, x = p & 127;
    const float ys = (float)(y * 63) / 127.0f;
    const float xs = (float)(x * 63) / 127.0f;
    const int iy0 = (int)ys, ix0 = (int)xs;
    const float fy = ys - (float)iy0, fx = xs - (float)ix0;
    const int iy1 = min(iy0 + 1, 63), ix1 = min(ix0 + 1, 63);
    const float* ob = outlo + n * 2 * 4096;
    float o01[2];
#pragma unroll
    for (int cc = 0; cc < 2; ++cc) {
        const float* oc = ob + cc * 4096;
        const float v00 = oc[iy0*64+ix0], v01 = oc[iy0*64+ix1];
        const float v10 = oc[iy1*64+ix0], v11 = oc[iy1*64+ix1];
        const float top = v00 + fx * (v01 - v00);
        const float bot = v10 + fx * (v11 - v10);
        o01[cc] = top + fy * (bot - top);
    }
    rec[g] = make_float4(o01[0], o01[1], f2sq, 0.f);
}

// 16-FMA dot of the register f1 fragment against one halo pixel's 4 f2 planes.
#define DOT16(fr, A, B, C, D, out)                                             \
    {                                                                          \
        float d0 = fr[0]*A.x, d1 = fr[1]*A.y, d2 = fr[2]*A.z, d3 = fr[3]*A.w;  \
        d0 = fmaf(fr[ 4], B.x, d0); d1 = fmaf(fr[ 5], B.y, d1);                \
        d2 = fmaf(fr[ 6], B.z, d2); d3 = fmaf(fr[ 7], B.w, d3);                \
        d0 = fmaf(fr[ 8], C.x, d0); d1 = fmaf(fr[ 9], C.y, d1);                \
        d2 = fmaf(fr[10], C.z, d2); d3 = fmaf(fr[11], C.w, d3);                \
        d0 = fmaf(fr[12], D.x, d0); d1 = fmaf(fr[13], D.y, d1);                \
        d2 = fmaf(fr[14], D.z, d2); d3 = fmaf(fr[15], D.w, d3);                \
        out = (d0 + d1) + (d2 + d3);                                           \
    }

// One tap: halo index h, ab value av (already in a register) -> accumulate.
#define TAP(h, av)                                                             \
    {                                                                          \
        const float4 A = sf[0][h], B = sf[1][h];                               \
        const float4 C = sf[2][h], D = sf[3][h];                               \
        float dot;                                                             \
        DOT16(f1r, A, B, C, D, dot);                                           \
        const float4 R = sf[4][h];                                             \
        float e = fmaf(-gd, R.z, fmaf(gd2, dot, c0));                          \
        e = fmaf(gs, (av), e);                                                 \
        const float w = __expf(e);                                             \
        s_ += w;                                                               \
        a0 = fmaf(w, R.x, a0);                                                 \
        a1 = fmaf(w, R.y, a1);                                                 \
    }

// ---------------------------------------------------------------------------
// Pass 2, v5: round-2 structure (proven 107.1 us) + 5-deep static software
// pipeline on the ab loads. Round-3's full 20-tap prefetch regressed
// (+3 us): 40+ live prefetch VGPRs under the launch_bounds(1024,4) 128-VGPR
// cap -> pressure. Middle ground: taps in 4 groups of 5; group g+1's five
// loads issue BEFORE group g's taps compute (full unroll -> all abv[]
// indices static). ~5-10 outstanding loads/wave, peak live prefetch regs
// ~10 over round-2's 68 -> ~80, no spill. q==3 tail load hoisted early.
// Thread map (verified rounds 1-3): px = t&255, quarter q = t>>8, taps
// tau = q+4*it (+ tau=80 on q3); linear partial merge via 9 KB LDS.
// Occupancy: 16 waves/CU.
// ---------------------------------------------------------------------------
__global__ __launch_bounds__(1024, 4) void pass2_kernel(
    const float4* __restrict__ f1p, const float4* __restrict__ f2p,
    const float4* __restrict__ rec, const float* __restrict__ ab,
    const float* __restrict__ gdp, const float* __restrict__ gsp,
    float* __restrict__ outp)
{
    __shared__ float4 sf[5][HPX];      // 46080 B: 4 f2 planes + (r0,r1,f2sq)
    __shared__ float part[3][3][256];  // 9216 B: quarters 1..3 partials

    const int t = threadIdx.x;         // 0..1023
    const int n = blockIdx.z;
    const int bx = blockIdx.x * TS, by = blockIdx.y * TS;

    // ---- fill halo (threads 0..575) ----
    if (t < HPX) {
        const int hy = t / 24, hx = t - hy * 24;
        int gy = by - 4 + hy; gy = gy < 0 ? -gy : (gy > 127 ? 254 - gy : gy);
        int gx = bx - 4 + hx; gx = gx < 0 ? -gx : (gx > 127 ? 254 - gx : gx);
        const int gp = n * HW + gy * 128 + gx;
        sf[0][t] = f2p[0 * NPIX + gp];
        sf[1][t] = f2p[1 * NPIX + gp];
        sf[2][t] = f2p[2 * NPIX + gp];
        sf[3][t] = f2p[3 * NPIX + gp];
        sf[4][t] = rec[gp];
    }
    __syncthreads();

    const float gd = gdp[0], gs = gsp[0];
    const int px = t & 255;            // pixel within tile
    const int q  = t >> 8;             // tap quarter 0..3 (wave-uniform)
    const int tx = px & 15, ty = px >> 4;
    const int p = (by + ty) * 128 + (bx + tx);
    const int g = n * HW + p;

    float f1r[16];
#pragma unroll
    for (int k = 0; k < 4; ++k) {
        const float4 v = f1p[k * NPIX + g];
        f1r[4*k] = v.x; f1r[4*k+1] = v.y; f1r[4*k+2] = v.z; f1r[4*k+3] = v.w;
    }
    float f1sq = 0.f;
#pragma unroll
    for (int o = 0; o < 16; ++o) f1sq = fmaf(f1r[o], f1r[o], f1sq);
    const float c0 = -gd * f1sq;
    const float gd2 = 2.0f * gd;

    float s_ = 0.f, a0 = 0.f, a1 = 0.f;

    // taps tau = q + 4*it, it = 0..19; tau=80 handled by q3 after.
    const float* abq = ab + (size_t)n * 81 * HW + p + (size_t)q * HW;
    float abv[20];
#pragma unroll
    for (int k = 0; k < 5; ++k) abv[k] = abq[(size_t)k * 4 * HW];   // group 0
    float ab80 = 0.f;
    if (q == 3) ab80 = abq[(size_t)77 * HW];   // tau = 3 + 77 = 80 (early)

    int jj = q;                                   // tap col j (wave-uniform)
    int h  = ty * HS + tx + q;                    // halo idx for (i=0, j=q)
#pragma unroll
    for (int gblk = 0; gblk < 4; ++gblk) {
        if (gblk < 3) {                           // issue group g+1's loads
#pragma unroll
            for (int k = 0; k < 5; ++k) {
                const int it = (gblk + 1) * 5 + k;
                abv[it] = abq[(size_t)it * 4 * HW];
            }
        }
#pragma unroll
        for (int k = 0; k < 5; ++k) {             // compute group g's taps
            TAP(h, abv[gblk * 5 + k]);
            jj += 4;
            const bool carry = (jj >= 9);
            jj -= carry ? 9 : 0;
            h  += carry ? 19 : 4;                 // +4, or +HS-5 on row carry
        }
    }
    if (q == 3) {                                 // extra tap tau=80 (i=8,j=8)
        const int h80 = (ty + 8) * HS + tx + 8;
        TAP(h80, ab80);
    }

    // ---- merge quarters (linear sums; verified rounds 1-3) ----
    if (q > 0) {
        part[q - 1][0][px] = s_;
        part[q - 1][1][px] = a0;
        part[q - 1][2][px] = a1;
    }
    __syncthreads();
    if (q == 0) {
#pragma unroll
        for (int k = 0; k < 3; ++k) {
            s_ += part[k][0][px];
            a0 += part[k][1][px];
            a1 += part[k][2][px];
        }
        const float inv = 1.0f / s_;
        outp[(n * 2 + 0) * HW + p] = a0 * inv;
        outp[(n * 2 + 1) * HW + p] = a1 * inv;
    }
}

extern "C" void kernel_launch(void* const* d_in, const int* in_sizes, int n_in,
                              void* d_out, int out_size, void* d_ws, size_t ws_size,
                              hipStream_t stream) {
    const float* delta = (const float*)d_in[0];   // [4,64,128,128]
    const float* outlo = (const float*)d_in[1];   // [4,2,64,64]
    const float* ab    = (const float*)d_in[2];   // [4,81,16384]
    const float* w1    = (const float*)d_in[3];   // [16,64]
    const float* b1    = (const float*)d_in[4];   // [16]
    const float* w2    = (const float*)d_in[5];   // [16,64]
    const float* b2    = (const float*)d_in[6];   // [16]
    const float* gd    = (const float*)d_in[7];   // scalar
    const float* gs    = (const float*)d_in[8];   // scalar
    float* outp = (float*)d_out;                  // [4,2,128,128]

    float4* f1p = (float4*)d_ws;                  // 4 MiB (4 planes x NPIX)
    float4* f2p = f1p + (size_t)4 * NPIX;         // 4 MiB
    float4* rec = f2p + (size_t)4 * NPIX;         // 1 MiB

    pass1_kernel<<<dim3(256), dim3(256), 0, stream>>>(delta, outlo, w1, b1, w2, b2,
                                                      f1p, f2p, rec);
    pass2_kernel<<<dim3(8, 8, 4), dim3(1024), 0, stream>>>(f1p, f2p, rec, ab,
                                                           gd, gs, outp);
}